// Round 1
// baseline (2390.252 us; speedup 1.0000x reference)
//
#include <hip/hip_runtime.h>
#include <math.h>

// Fused OpenMax classifier, fp32 baseline.
// Per block: 32 rows. LDS: x-tile [32][260] (reused for act tile) + h-tile [32][260].
// Layer1: [32,256]x[256,256], layer2: [32,256]x[256,128], layer3+epilogue per (row,class).

#define BM 32

__global__ __launch_bounds__(256, 2)
void openmax_fused(const float* __restrict__ x,
                   const float* __restrict__ W1, const float* __restrict__ b1,
                   const float* __restrict__ W2, const float* __restrict__ b2,
                   const float* __restrict__ W3, const float* __restrict__ b3,
                   const float* __restrict__ walpha, const float* __restrict__ wbeta,
                   const float* __restrict__ wtau, const float* __restrict__ AV,
                   float* __restrict__ out)
{
    __shared__ float hs[BM][260];   // h tile (relu(x@W1+b1)), padded: bank = (4r + k) % 32
    __shared__ float xa[BM][260];   // x tile, later reused as act tile

    const int tid = threadIdx.x;
    const int row0 = blockIdx.x * BM;

    // ---- stage X tile: 32 rows x 256 cols, coalesced float4 ----
    {
        const float4* xg = reinterpret_cast<const float4*>(x + (size_t)row0 * 256);
        #pragma unroll
        for (int i = 0; i < 8; ++i) {
            int idx = i * 256 + tid;          // float4 index within tile (2048 total)
            int r  = idx >> 6;                // 64 float4 per row
            int c4 = (idx & 63) << 2;
            float4 v = xg[idx];
            *reinterpret_cast<float4*>(&xa[r][c4]) = v;   // row stride 260*4B is 16B-aligned
        }
    }
    __syncthreads();

    const int ty = tid >> 4;   // 0..15
    const int tx = tid & 15;   // 0..15

    // ---- layer 1: h = relu(x @ W1 + b1); thread: 2 rows x 16 cols ----
    {
        const int r0 = ty * 2;
        const int c0 = tx * 16;
        float acc0[16], acc1[16];
        #pragma unroll
        for (int j = 0; j < 16; ++j) { acc0[j] = 0.f; acc1[j] = 0.f; }

        for (int k = 0; k < 256; k += 4) {
            float a0[4], a1[4];
            *reinterpret_cast<float4*>(a0) = *reinterpret_cast<const float4*>(&xa[r0][k]);
            *reinterpret_cast<float4*>(a1) = *reinterpret_cast<const float4*>(&xa[r0 + 1][k]);
            #pragma unroll
            for (int kk = 0; kk < 4; ++kk) {
                const float* wr = W1 + (k + kk) * 256 + c0;
                float w[16];
                *reinterpret_cast<float4*>(&w[0])  = *reinterpret_cast<const float4*>(wr);
                *reinterpret_cast<float4*>(&w[4])  = *reinterpret_cast<const float4*>(wr + 4);
                *reinterpret_cast<float4*>(&w[8])  = *reinterpret_cast<const float4*>(wr + 8);
                *reinterpret_cast<float4*>(&w[12]) = *reinterpret_cast<const float4*>(wr + 12);
                #pragma unroll
                for (int j = 0; j < 16; ++j) {
                    acc0[j] = fmaf(a0[kk], w[j], acc0[j]);
                    acc1[j] = fmaf(a1[kk], w[j], acc1[j]);
                }
            }
        }
        #pragma unroll
        for (int j = 0; j < 16; ++j) {
            float bb = b1[c0 + j];
            hs[r0][c0 + j]     = fmaxf(acc0[j] + bb, 0.f);
            hs[r0 + 1][c0 + j] = fmaxf(acc1[j] + bb, 0.f);
        }
    }
    __syncthreads();

    // ---- layer 2: act = relu(h @ W2 + b2); thread: 2 rows x 8 cols; result into xa ----
    {
        const int r0 = ty * 2;
        const int c0 = tx * 8;
        float acc0[8], acc1[8];
        #pragma unroll
        for (int j = 0; j < 8; ++j) { acc0[j] = 0.f; acc1[j] = 0.f; }

        for (int k = 0; k < 256; k += 4) {
            float a0[4], a1[4];
            *reinterpret_cast<float4*>(a0) = *reinterpret_cast<const float4*>(&hs[r0][k]);
            *reinterpret_cast<float4*>(a1) = *reinterpret_cast<const float4*>(&hs[r0 + 1][k]);
            #pragma unroll
            for (int kk = 0; kk < 4; ++kk) {
                const float* wr = W2 + (k + kk) * 128 + c0;
                float w[8];
                *reinterpret_cast<float4*>(&w[0]) = *reinterpret_cast<const float4*>(wr);
                *reinterpret_cast<float4*>(&w[4]) = *reinterpret_cast<const float4*>(wr + 4);
                #pragma unroll
                for (int j = 0; j < 8; ++j) {
                    acc0[j] = fmaf(a0[kk], w[j], acc0[j]);
                    acc1[j] = fmaf(a1[kk], w[j], acc1[j]);
                }
            }
        }
        __syncthreads();   // all reads of hs done before we also finish; xa writes are to dead x-tile
        #pragma unroll
        for (int j = 0; j < 8; ++j) {
            float bb = b2[c0 + j];
            xa[r0][c0 + j]     = fmaxf(acc0[j] + bb, 0.f);
            xa[r0 + 1][c0 + j] = fmaxf(acc1[j] + bb, 0.f);
        }
    }
    __syncthreads();

    // ---- layer 3 + OpenMax epilogue: thread = (row, class) ----
    {
        const int row = tid >> 3;   // 0..31
        const int c   = tid & 7;    // 0..7
        float lg = 0.f, dt = 0.f, a2 = 0.f, v2 = 0.f;
        for (int k = 0; k < 128; ++k) {
            float a   = xa[row][k];
            float w3v = W3[k * 8 + c];
            float avv = AV[c * 128 + k];
            lg = fmaf(a, w3v, lg);
            dt = fmaf(a, avv, dt);
            a2 = fmaf(a, a, a2);
            v2 = fmaf(avv, avv, v2);
        }
        lg += b3[c];
        float d2   = a2 - 2.f * dt + v2;
        float dist = sqrtf(fmaxf(d2, 0.f));
        float sb   = fmaxf(wbeta[c], 1e-6f);
        float sx   = fmaxf(dist - wtau[c], 0.f);
        float cdf  = 1.f - expf(-powf(sx / sb, walpha[c]));

        // max over the 8 classes (lanes c=0..7 of this row)
        float m = cdf;
        #pragma unroll
        for (int off = 4; off >= 1; off >>= 1)
            m = fmaxf(m, __shfl_xor(m, off, 8));

        float scale = (m > 0.5f) ? (1.f - m) : 1.f;
        out[(size_t)(row0 + row) * 8 + c] = lg * scale;
    }
}

extern "C" void kernel_launch(void* const* d_in, const int* in_sizes, int n_in,
                              void* d_out, int out_size, void* d_ws, size_t ws_size,
                              hipStream_t stream) {
    const float* x      = (const float*)d_in[0];
    const float* W1     = (const float*)d_in[1];
    const float* b1     = (const float*)d_in[2];
    const float* W2     = (const float*)d_in[3];
    const float* b2     = (const float*)d_in[4];
    const float* W3     = (const float*)d_in[5];
    const float* b3     = (const float*)d_in[6];
    const float* walpha = (const float*)d_in[7];
    const float* wbeta  = (const float*)d_in[8];
    const float* wtau   = (const float*)d_in[9];
    const float* AV     = (const float*)d_in[10];
    float* out = (float*)d_out;

    const int B = in_sizes[0] / 256;      // 262144 rows
    const int grid = B / BM;              // 8192 blocks

    openmax_fused<<<grid, 256, 0, stream>>>(x, W1, b1, W2, b2, W3, b3,
                                            walpha, wbeta, wtau, AV, out);
}

// Round 2
// 152.263 us; speedup vs baseline: 15.6982x; 15.6982x over previous
//
#include <hip/hip_runtime.h>
#include <hip/hip_bf16.h>
#include <math.h>

typedef __attribute__((ext_vector_type(8)))  short  short8;
typedef __attribute__((ext_vector_type(4)))  short  short4v;
typedef __attribute__((ext_vector_type(16))) float  f32x16;
typedef __attribute__((ext_vector_type(4)))  int    int4v;

__device__ __forceinline__ short f2bs(float f) {
    __hip_bfloat16 h = __float2bfloat16(f);
    return __builtin_bit_cast(short, h);
}

#define MFMA32(A, B, C) __builtin_amdgcn_mfma_f32_32x32x16_bf16((A), (B), (C), 0, 0, 0)

// ---------------- prep: pack weights to bf16 MFMA-A layout in ws ----------------
// ws layout (bytes):
//   [0, 131072)       W1tp: [kc 0..31][m 0..255][8] bf16,  = W1^T[m][kc*8+i] = W1[(kc*8+i)*256+m]
//   [131072, 196608)  W2tp: [kc 0..31][m 0..127][8] bf16,  = W2[(kc*8+i)*128+m]
//   [196608, 204800)  B3p : [kc 0..15][m 0..31 ][8] bf16,  m<8: W3[k*8+m]; 8<=m<16: AV[(m-8)*128+k]; else 0
//   [204800, 204832)  v2  : float[8] = sum_k AV[c][k]^2
__global__ void prep_pack(const float* __restrict__ W1, const float* __restrict__ W2,
                          const float* __restrict__ W3, const float* __restrict__ AV,
                          short* __restrict__ wp) {
    int idx = blockIdx.x * 256 + threadIdx.x;
    if (idx < 65536) {
        int i = idx & 7, m = (idx >> 3) & 255, kc = idx >> 11;
        wp[idx] = f2bs(W1[(kc * 8 + i) * 256 + m]);
    } else if (idx < 98304) {
        int j = idx - 65536;
        int i = j & 7, m = (j >> 3) & 127, kc = j >> 10;
        wp[idx] = f2bs(W2[(kc * 8 + i) * 128 + m]);
    } else if (idx < 102400) {
        int j = idx - 98304;
        int i = j & 7, m = (j >> 3) & 31, kc = j >> 8;
        int k = kc * 8 + i;
        float v = 0.f;
        if (m < 8)       v = W3[k * 8 + m];
        else if (m < 16) v = AV[(m - 8) * 128 + k];
        wp[idx] = f2bs(v);
    }
}

__global__ void prep_v2(const float* __restrict__ AV, float* __restrict__ v2) {
    int l = threadIdx.x;
    int c = l >> 3, j = l & 7;
    float s = 0.f;
    for (int k = j * 16; k < j * 16 + 16; ++k) { float a = AV[c * 128 + k]; s += a * a; }
    s += __shfl_xor(s, 1); s += __shfl_xor(s, 2); s += __shfl_xor(s, 4);
    if (j == 0) v2[c] = s;
}

// ---------------- main fused kernel ----------------
// Block: 64 rows, 256 threads (4 waves). Swapped GEMMs with mfma_f32_32x32x16_bf16:
//   GEMM1': h^T  = W1tp(A) @ x^T(B from LDS)   M=256 N=64 K=256
//   GEMM2': act^T= W2tp(A) @ h(B from LDS)     M=128 N=64 K=256
//   GEMM3': D3   = B3p(A)  @ act(B from LDS)   M=32(8 logits+8 dots) N=64 K=128
// LDS 64KB: x_bf16[64][256] @0 (act[64][128] + a2p[4][64] reuse it), h[64][256] @32768.
// All tiles chunk-swizzled: 16B chunk c of row r stored at slot c^(r&7)  -> conflict-free b128.
#define LDS_H 32768

__global__ __launch_bounds__(256, 2)
void openmax_mfma(const float* __restrict__ x,
                  const float* __restrict__ b1, const float* __restrict__ b2,
                  const float* __restrict__ b3,
                  const float* __restrict__ walpha, const float* __restrict__ wbeta,
                  const float* __restrict__ wtau,
                  const short* __restrict__ wpack, const float* __restrict__ v2g,
                  float* __restrict__ out) {
    __shared__ __align__(16) char smem[65536];
    const int tid = threadIdx.x;
    const int l = tid & 63, wv = tid >> 6;
    const int lo = l & 31, g = l >> 5;
    const long row0 = (long)blockIdx.x * 64;

    // ---- stage x tile (64 rows x 256 f32) as bf16, chunk-swizzled ----
    {
        const float4* xg = (const float4*)(x + row0 * 256);
        #pragma unroll
        for (int i = 0; i < 16; ++i) {
            int fc = i * 256 + tid;          // 16B-f32-chunk index (4 floats)
            float4 v = xg[fc];
            int row = fc >> 6, c4 = fc & 63;
            int cb = c4 >> 1, half = c4 & 1; // bf16 16B chunk + half
            short4v s;
            s[0] = f2bs(v.x); s[1] = f2bs(v.y); s[2] = f2bs(v.z); s[3] = f2bs(v.w);
            int off = row * 512 + ((cb ^ (row & 7)) << 4) + half * 8;
            *(short4v*)(smem + off) = s;
        }
    }
    __syncthreads();

    // ---- GEMM1': h^T = W1^T @ x^T ----
    {
        const int4v* Ap = (const int4v*)wpack;
        f32x16 acc00, acc01, acc10, acc11;
        #pragma unroll
        for (int i = 0; i < 16; ++i) { acc00[i] = 0.f; acc01[i] = 0.f; acc10[i] = 0.f; acc11[i] = 0.f; }
        const int mt0 = wv * 2;
        const int aRow = mt0 * 32 + lo;
        #pragma unroll
        for (int ks = 0; ks < 16; ++ks) {
            int kc = ks * 2 + g;
            short8 a0 = __builtin_bit_cast(short8, Ap[kc * 256 + aRow]);
            short8 a1 = __builtin_bit_cast(short8, Ap[kc * 256 + aRow + 32]);
            int r0 = lo, r1 = 32 + lo;
            short8 bb0 = *(const short8*)(smem + r0 * 512 + ((kc ^ (r0 & 7)) << 4));
            short8 bb1 = *(const short8*)(smem + r1 * 512 + ((kc ^ (r1 & 7)) << 4));
            acc00 = MFMA32(a0, bb0, acc00);
            acc01 = MFMA32(a0, bb1, acc01);
            acc10 = MFMA32(a1, bb0, acc10);
            acc11 = MFMA32(a1, bb1, acc11);
        }
        // bias + relu + pack to h LDS (b64 stores, conflict-free via chunk swizzle)
        #pragma unroll
        for (int mt = 0; mt < 2; ++mt) {
            float bia[16];
            #pragma unroll
            for (int r = 0; r < 16; ++r)
                bia[r] = b1[(mt0 + mt) * 32 + 4 * g + (r & 3) + 8 * (r >> 2)];
            #pragma unroll
            for (int nt = 0; nt < 2; ++nt) {
                const f32x16& A = (mt == 0) ? (nt == 0 ? acc00 : acc01)
                                            : (nt == 0 ? acc10 : acc11);
                int b = nt * 32 + lo;
                int base = LDS_H + b * 512 + g * 8;
                #pragma unroll
                for (int q = 0; q < 4; ++q) {
                    float v0 = fmaxf(A[4 * q + 0] + bia[4 * q + 0], 0.f);
                    float v1 = fmaxf(A[4 * q + 1] + bia[4 * q + 1], 0.f);
                    float v2_ = fmaxf(A[4 * q + 2] + bia[4 * q + 2], 0.f);
                    float v3 = fmaxf(A[4 * q + 3] + bia[4 * q + 3], 0.f);
                    short4v s; s[0] = f2bs(v0); s[1] = f2bs(v1); s[2] = f2bs(v2_); s[3] = f2bs(v3);
                    int hc = (mt0 + mt) * 4 + q;
                    *(short4v*)(smem + base + ((hc ^ (b & 7)) << 4)) = s;
                }
            }
        }
    }
    __syncthreads();

    // ---- GEMM2': act^T = W2^T @ h ; store act bf16 into (dead) x region + a2 partials ----
    {
        const int4v* Ap = (const int4v*)(wpack + 65536);
        f32x16 acc0, acc1;
        #pragma unroll
        for (int i = 0; i < 16; ++i) { acc0[i] = 0.f; acc1[i] = 0.f; }
        const int aRow = wv * 32 + lo;
        #pragma unroll
        for (int ks = 0; ks < 16; ++ks) {
            int kc = ks * 2 + g;
            short8 a = __builtin_bit_cast(short8, Ap[kc * 128 + aRow]);
            int r0 = lo, r1 = 32 + lo;
            short8 bb0 = *(const short8*)(smem + LDS_H + r0 * 512 + ((kc ^ (r0 & 7)) << 4));
            short8 bb1 = *(const short8*)(smem + LDS_H + r1 * 512 + ((kc ^ (r1 & 7)) << 4));
            acc0 = MFMA32(a, bb0, acc0);
            acc1 = MFMA32(a, bb1, acc1);
        }
        float bia[16];
        #pragma unroll
        for (int r = 0; r < 16; ++r)
            bia[r] = b2[wv * 32 + 4 * g + (r & 3) + 8 * (r >> 2)];
        #pragma unroll
        for (int nt = 0; nt < 2; ++nt) {
            const f32x16& A = nt == 0 ? acc0 : acc1;
            int b = nt * 32 + lo;
            int base = b * 256 + g * 8;
            float ss = 0.f;
            #pragma unroll
            for (int q = 0; q < 4; ++q) {
                float v0 = fmaxf(A[4 * q + 0] + bia[4 * q + 0], 0.f);
                float v1 = fmaxf(A[4 * q + 1] + bia[4 * q + 1], 0.f);
                float v2_ = fmaxf(A[4 * q + 2] + bia[4 * q + 2], 0.f);
                float v3 = fmaxf(A[4 * q + 3] + bia[4 * q + 3], 0.f);
                ss += v0 * v0 + v1 * v1 + v2_ * v2_ + v3 * v3;
                short4v s; s[0] = f2bs(v0); s[1] = f2bs(v1); s[2] = f2bs(v2_); s[3] = f2bs(v3);
                int hc = wv * 4 + q;
                *(short4v*)(smem + base + ((hc ^ (b & 7)) << 4)) = s;
            }
            ss += __shfl_xor(ss, 32);
            if (g == 0) *(float*)(smem + 16384 + (wv * 64 + b) * 4) = ss;
        }
    }
    __syncthreads();

    // ---- GEMM3' + OpenMax epilogue (waves 0,1; wave wv owns batch rows wv*32..+32) ----
    if (wv < 2) {
        const int4v* Ap = (const int4v*)(wpack + 98304);
        f32x16 acc;
        #pragma unroll
        for (int i = 0; i < 16; ++i) acc[i] = 0.f;
        const int b = wv * 32 + lo;
        #pragma unroll
        for (int ks = 0; ks < 8; ++ks) {
            int kc = ks * 2 + g;
            short8 a = __builtin_bit_cast(short8, Ap[kc * 32 + lo]);
            short8 bb = *(const short8*)(smem + b * 256 + ((kc ^ (b & 7)) << 4));
            acc = MFMA32(a, bb, acc);
        }
        // lane holds: logits classes 4g+j in acc[j], dots classes 4g+j in acc[4+j]
        float oth[8];
        #pragma unroll
        for (int j = 0; j < 8; ++j) oth[j] = __shfl_xor(acc[j], 32);

        float a2v = 0.f;
        #pragma unroll
        for (int wq = 0; wq < 4; ++wq)
            a2v += *(const float*)(smem + 16384 + (wq * 64 + b) * 4);

        float m = 0.f, outv[8];
        #pragma unroll
        for (int c = 0; c < 8; ++c) {
            float lgv = ((c >> 2) == g) ? acc[c & 3]     : oth[c & 3];
            float dtv = ((c >> 2) == g) ? acc[4 + (c & 3)] : oth[4 + (c & 3)];
            float d2 = a2v - 2.f * dtv + v2g[c];
            float dist = sqrtf(fmaxf(d2, 0.f));
            float sb = fmaxf(wbeta[c], 1e-6f);
            float sx = fmaxf(dist - wtau[c], 0.f);
            float cdf = 1.f - expf(-powf(sx / sb, walpha[c]));
            m = fmaxf(m, cdf);
            outv[c] = lgv + b3[c];
        }
        float scale = (m > 0.5f) ? (1.f - m) : 1.f;
        if (g == 0) {
            float4 o0 = { outv[0] * scale, outv[1] * scale, outv[2] * scale, outv[3] * scale };
            float4 o1 = { outv[4] * scale, outv[5] * scale, outv[6] * scale, outv[7] * scale };
            float4* op = (float4*)(out + (row0 + b) * 8);
            op[0] = o0; op[1] = o1;
        }
    }
}

extern "C" void kernel_launch(void* const* d_in, const int* in_sizes, int n_in,
                              void* d_out, int out_size, void* d_ws, size_t ws_size,
                              hipStream_t stream) {
    const float* x      = (const float*)d_in[0];
    const float* W1     = (const float*)d_in[1];
    const float* b1     = (const float*)d_in[2];
    const float* W2     = (const float*)d_in[3];
    const float* b2     = (const float*)d_in[4];
    const float* W3     = (const float*)d_in[5];
    const float* b3     = (const float*)d_in[6];
    const float* walpha = (const float*)d_in[7];
    const float* wbeta  = (const float*)d_in[8];
    const float* wtau   = (const float*)d_in[9];
    const float* AV     = (const float*)d_in[10];
    float* out = (float*)d_out;

    short* wpack = (short*)d_ws;
    float* v2    = (float*)((char*)d_ws + 204800);

    prep_pack<<<400, 256, 0, stream>>>(W1, W2, W3, AV, wpack);
    prep_v2<<<1, 64, 0, stream>>>(AV, v2);

    const int B = in_sizes[0] / 256;   // 262144
    openmax_mfma<<<B / 64, 256, 0, stream>>>(x, b1, b2, b3, walpha, wbeta, wtau,
                                             wpack, v2, out);
}

// Round 3
// 138.986 us; speedup vs baseline: 17.1978x; 1.0955x over previous
//
#include <hip/hip_runtime.h>
#include <hip/hip_bf16.h>
#include <math.h>

typedef __attribute__((ext_vector_type(8)))  short  short8;
typedef __attribute__((ext_vector_type(4)))  short  short4v;
typedef __attribute__((ext_vector_type(16))) float  f32x16;
typedef __attribute__((ext_vector_type(4)))  int    int4v;

__device__ __forceinline__ short f2bs(float f) {
    __hip_bfloat16 h = __float2bfloat16(f);
    return __builtin_bit_cast(short, h);
}

#define MFMA32(A, B, C) __builtin_amdgcn_mfma_f32_32x32x16_bf16((A), (B), (C), 0, 0, 0)

// ---------------- prep: pack weights to bf16 MFMA-A layout in ws ----------------
// ws layout (bytes):
//   [0, 131072)       W1tp: [kc 0..31][m 0..255][8] bf16,  = W1[(kc*8+i)*256+m]
//   [131072, 196608)  W2tp: [kc 0..31][m 0..127][8] bf16,  = W2[(kc*8+i)*128+m]
//   [196608, 204800)  B3p : [kc 0..15][m 0..31 ][8] bf16,  m<8: W3[k*8+m]; 8<=m<16: AV[(m-8)*128+k]; else 0
//   [204800, 204832)  v2  : float[8] = sum_k AV[c][k]^2
__global__ void prep_pack(const float* __restrict__ W1, const float* __restrict__ W2,
                          const float* __restrict__ W3, const float* __restrict__ AV,
                          short* __restrict__ wp) {
    int idx = blockIdx.x * 256 + threadIdx.x;
    if (idx < 65536) {
        int i = idx & 7, m = (idx >> 3) & 255, kc = idx >> 11;
        wp[idx] = f2bs(W1[(kc * 8 + i) * 256 + m]);
    } else if (idx < 98304) {
        int j = idx - 65536;
        int i = j & 7, m = (j >> 3) & 127, kc = j >> 10;
        wp[idx] = f2bs(W2[(kc * 8 + i) * 128 + m]);
    } else if (idx < 102400) {
        int j = idx - 98304;
        int i = j & 7, m = (j >> 3) & 31, kc = j >> 8;
        int k = kc * 8 + i;
        float v = 0.f;
        if (m < 8)       v = W3[k * 8 + m];
        else if (m < 16) v = AV[(m - 8) * 128 + k];
        wp[idx] = f2bs(v);
    }
}

__global__ void prep_v2(const float* __restrict__ AV, float* __restrict__ v2) {
    int l = threadIdx.x;
    int c = l >> 3, j = l & 7;
    float s = 0.f;
    for (int k = j * 16; k < j * 16 + 16; ++k) { float a = AV[c * 128 + k]; s += a * a; }
    s += __shfl_xor(s, 1); s += __shfl_xor(s, 2); s += __shfl_xor(s, 4);
    if (j == 0) v2[c] = s;
}

// ---------------- main fused kernel ----------------
// Block: 32 rows, 256 threads (4 waves), LDS exactly 32KB -> 5 blocks/CU (20 waves, 62.5%).
// Swapped GEMMs with mfma_f32_32x32x16_bf16:
//   GEMM1': h^T  = W1tp(A) @ x^T(B)   M=256 N=32 K=256   (wave wv: m-tiles 2wv,2wv+1)
//   GEMM2': act^T= W2tp(A) @ h(B)     M=128 N=32 K=256   (wave wv: m-tile wv)
//   GEMM3': D3   = B3p(A)  @ act(B)   M=32 N=32 K=128    (wave 0 only)
// LDS: x bf16 [32 rows][512B] @0; h @16384; act [32][256B] reuses @0; a2 partials @8192.
// 16B chunk c of row r stored at slot c^(r&7) -> conflict-free ds_read_b128.
#define LDS_H 16384

__global__ __launch_bounds__(256, 5)
void openmax_mfma(const float* __restrict__ x,
                  const float* __restrict__ b1, const float* __restrict__ b2,
                  const float* __restrict__ b3,
                  const float* __restrict__ walpha, const float* __restrict__ wbeta,
                  const float* __restrict__ wtau,
                  const short* __restrict__ wpack, const float* __restrict__ v2g,
                  float* __restrict__ out) {
    __shared__ __align__(16) char smem[32768];
    const int tid = threadIdx.x;
    const int l = tid & 63, wv = tid >> 6;
    const int lo = l & 31, g = l >> 5;
    const long row0 = (long)blockIdx.x * 32;

    // ---- stage x tile (32 rows x 256 f32) as bf16, chunk-swizzled ----
    {
        const float4* xg = (const float4*)(x + row0 * 256);
        #pragma unroll
        for (int i = 0; i < 8; ++i) {
            int fc = i * 256 + tid;          // f32 16B-chunk index (2048 total)
            float4 v = xg[fc];
            int row = fc >> 6, c4 = fc & 63;
            int cb = c4 >> 1, half = c4 & 1;
            short4v s;
            s[0] = f2bs(v.x); s[1] = f2bs(v.y); s[2] = f2bs(v.z); s[3] = f2bs(v.w);
            int off = row * 512 + ((cb ^ (row & 7)) << 4) + half * 8;
            *(short4v*)(smem + off) = s;
        }
    }
    __syncthreads();

    // ---- GEMM1': h^T = W1^T @ x^T ----
    {
        const int4v* Ap = (const int4v*)wpack;
        f32x16 acc0, acc1;
        #pragma unroll
        for (int i = 0; i < 16; ++i) { acc0[i] = 0.f; acc1[i] = 0.f; }
        const int mt0 = wv * 2;
        const int aRow = mt0 * 32 + lo;
        #pragma unroll
        for (int ks = 0; ks < 16; ++ks) {
            int kc = ks * 2 + g;
            short8 a0 = __builtin_bit_cast(short8, Ap[kc * 256 + aRow]);
            short8 a1 = __builtin_bit_cast(short8, Ap[kc * 256 + aRow + 32]);
            short8 bb = *(const short8*)(smem + lo * 512 + ((kc ^ (lo & 7)) << 4));
            acc0 = MFMA32(a0, bb, acc0);
            acc1 = MFMA32(a1, bb, acc1);
        }
        // bias + relu + pack to h LDS (b64 stores, chunk-swizzled)
        #pragma unroll
        for (int mt = 0; mt < 2; ++mt) {
            const f32x16& A = (mt == 0) ? acc0 : acc1;
            float bia[16];
            #pragma unroll
            for (int r = 0; r < 16; ++r)
                bia[r] = b1[(mt0 + mt) * 32 + 4 * g + (r & 3) + 8 * (r >> 2)];
            int base = LDS_H + lo * 512 + g * 8;
            #pragma unroll
            for (int q = 0; q < 4; ++q) {
                float v0 = fmaxf(A[4 * q + 0] + bia[4 * q + 0], 0.f);
                float v1 = fmaxf(A[4 * q + 1] + bia[4 * q + 1], 0.f);
                float v2_ = fmaxf(A[4 * q + 2] + bia[4 * q + 2], 0.f);
                float v3 = fmaxf(A[4 * q + 3] + bia[4 * q + 3], 0.f);
                short4v s; s[0] = f2bs(v0); s[1] = f2bs(v1); s[2] = f2bs(v2_); s[3] = f2bs(v3);
                int hc = (mt0 + mt) * 4 + q;
                *(short4v*)(smem + base + ((hc ^ (lo & 7)) << 4)) = s;
            }
        }
    }
    __syncthreads();

    // ---- GEMM2': act^T = W2^T @ h ; act bf16 into dead x region + a2 partials ----
    {
        const int4v* Ap = (const int4v*)(wpack + 65536);
        f32x16 acc;
        #pragma unroll
        for (int i = 0; i < 16; ++i) acc[i] = 0.f;
        const int aRow = wv * 32 + lo;
        #pragma unroll
        for (int ks = 0; ks < 16; ++ks) {
            int kc = ks * 2 + g;
            short8 a = __builtin_bit_cast(short8, Ap[kc * 128 + aRow]);
            short8 bb = *(const short8*)(smem + LDS_H + lo * 512 + ((kc ^ (lo & 7)) << 4));
            acc = MFMA32(a, bb, acc);
        }
        float bia[16];
        #pragma unroll
        for (int r = 0; r < 16; ++r)
            bia[r] = b2[wv * 32 + 4 * g + (r & 3) + 8 * (r >> 2)];
        int base = lo * 256 + g * 8;
        float ss = 0.f;
        #pragma unroll
        for (int q = 0; q < 4; ++q) {
            float v0 = fmaxf(acc[4 * q + 0] + bia[4 * q + 0], 0.f);
            float v1 = fmaxf(acc[4 * q + 1] + bia[4 * q + 1], 0.f);
            float v2_ = fmaxf(acc[4 * q + 2] + bia[4 * q + 2], 0.f);
            float v3 = fmaxf(acc[4 * q + 3] + bia[4 * q + 3], 0.f);
            ss += v0 * v0 + v1 * v1 + v2_ * v2_ + v3 * v3;
            short4v s; s[0] = f2bs(v0); s[1] = f2bs(v1); s[2] = f2bs(v2_); s[3] = f2bs(v3);
            int hc = wv * 4 + q;
            *(short4v*)(smem + base + ((hc ^ (lo & 7)) << 4)) = s;
        }
        ss += __shfl_xor(ss, 32);
        if (g == 0) *(float*)(smem + 8192 + (wv * 32 + lo) * 4) = ss;
    }
    __syncthreads();

    // ---- GEMM3' + OpenMax epilogue (wave 0 only) ----
    if (wv == 0) {
        const int4v* Ap = (const int4v*)(wpack + 98304);
        f32x16 acc;
        #pragma unroll
        for (int i = 0; i < 16; ++i) acc[i] = 0.f;
        #pragma unroll
        for (int ks = 0; ks < 8; ++ks) {
            int kc = ks * 2 + g;
            short8 a = __builtin_bit_cast(short8, Ap[kc * 32 + lo]);
            short8 bb = *(const short8*)(smem + lo * 256 + ((kc ^ (lo & 7)) << 4));
            acc = MFMA32(a, bb, acc);
        }
        // lane holds: logits classes 4g+j in acc[j], dots classes 4g+j in acc[4+j]
        float oth[8];
        #pragma unroll
        for (int j = 0; j < 8; ++j) oth[j] = __shfl_xor(acc[j], 32);

        float a2v = 0.f;
        #pragma unroll
        for (int wq = 0; wq < 4; ++wq)
            a2v += *(const float*)(smem + 8192 + (wq * 32 + lo) * 4);

        float m = 0.f, outv[8];
        #pragma unroll
        for (int c = 0; c < 8; ++c) {
            float lgv = ((c >> 2) == g) ? acc[c & 3]       : oth[c & 3];
            float dtv = ((c >> 2) == g) ? acc[4 + (c & 3)] : oth[4 + (c & 3)];
            float d2 = a2v - 2.f * dtv + v2g[c];
            float dist = sqrtf(fmaxf(d2, 0.f));
            float sb = fmaxf(wbeta[c], 1e-6f);
            float sx = fmaxf(dist - wtau[c], 0.f);
            float cdf = 1.f - expf(-powf(sx / sb, walpha[c]));
            m = fmaxf(m, cdf);
            outv[c] = lgv + b3[c];
        }
        float scale = (m > 0.5f) ? (1.f - m) : 1.f;
        if (g == 0) {
            float4 o0 = { outv[0] * scale, outv[1] * scale, outv[2] * scale, outv[3] * scale };
            float4 o1 = { outv[4] * scale, outv[5] * scale, outv[6] * scale, outv[7] * scale };
            float4* op = (float4*)(out + (row0 + lo) * 8);
            op[0] = o0; op[1] = o1;
        }
    }
}

extern "C" void kernel_launch(void* const* d_in, const int* in_sizes, int n_in,
                              void* d_out, int out_size, void* d_ws, size_t ws_size,
                              hipStream_t stream) {
    const float* x      = (const float*)d_in[0];
    const float* W1     = (const float*)d_in[1];
    const float* b1     = (const float*)d_in[2];
    const float* W2     = (const float*)d_in[3];
    const float* b2     = (const float*)d_in[4];
    const float* W3     = (const float*)d_in[5];
    const float* b3     = (const float*)d_in[6];
    const float* walpha = (const float*)d_in[7];
    const float* wbeta  = (const float*)d_in[8];
    const float* wtau   = (const float*)d_in[9];
    const float* AV     = (const float*)d_in[10];
    float* out = (float*)d_out;

    short* wpack = (short*)d_ws;
    float* v2    = (float*)((char*)d_ws + 204800);

    prep_pack<<<400, 256, 0, stream>>>(W1, W2, W3, AV, wpack);
    prep_v2<<<1, 64, 0, stream>>>(AV, v2);

    const int B = in_sizes[0] / 256;   // 262144
    openmax_mfma<<<B / 32, 256, 0, stream>>>(x, b1, b2, b3, walpha, wbeta, wtau,
                                             wpack, v2, out);
}

// Round 4
// 122.458 us; speedup vs baseline: 19.5190x; 1.1350x over previous
//
#include <hip/hip_runtime.h>
#include <hip/hip_bf16.h>
#include <math.h>

typedef __attribute__((ext_vector_type(8)))  short  short8;
typedef __attribute__((ext_vector_type(4)))  short  short4v;
typedef __attribute__((ext_vector_type(16))) float  f32x16;
typedef __attribute__((ext_vector_type(4)))  int    int4v;

__device__ __forceinline__ short f2bs(float f) {
    __hip_bfloat16 h = __float2bfloat16(f);
    return __builtin_bit_cast(short, h);
}

#define MFMA32(A, B, C) __builtin_amdgcn_mfma_f32_32x32x16_bf16((A), (B), (C), 0, 0, 0)

// ---------------- prep: pack weights to bf16 MFMA-A layout in ws ----------------
// ws layout (bytes):
//   [0, 131072)       W1tp: [kc 0..31][m 0..255][8] bf16,  = W1[(kc*8+i)*256+m]
//   [131072, 196608)  W2tp: [kc 0..31][m 0..127][8] bf16,  = W2[(kc*8+i)*128+m]
//   [196608, 204800)  B3p : [kc 0..15][m 0..31 ][8] bf16,  m<8: W3[k*8+m]; 8<=m<16: AV[(m-8)*128+k]; else 0
//   [204800, 204832)  v2  : float[8] = sum_k AV[c][k]^2
__global__ void prep_pack(const float* __restrict__ W1, const float* __restrict__ W2,
                          const float* __restrict__ W3, const float* __restrict__ AV,
                          short* __restrict__ wp) {
    int idx = blockIdx.x * 256 + threadIdx.x;
    if (idx < 65536) {
        int i = idx & 7, m = (idx >> 3) & 255, kc = idx >> 11;
        wp[idx] = f2bs(W1[(kc * 8 + i) * 256 + m]);
    } else if (idx < 98304) {
        int j = idx - 65536;
        int i = j & 7, m = (j >> 3) & 127, kc = j >> 10;
        wp[idx] = f2bs(W2[(kc * 8 + i) * 128 + m]);
    } else if (idx < 102400) {
        int j = idx - 98304;
        int i = j & 7, m = (j >> 3) & 31, kc = j >> 8;
        int k = kc * 8 + i;
        float v = 0.f;
        if (m < 8)       v = W3[k * 8 + m];
        else if (m < 16) v = AV[(m - 8) * 128 + k];
        wp[idx] = f2bs(v);
    }
}

__global__ void prep_v2(const float* __restrict__ AV, float* __restrict__ v2) {
    int l = threadIdx.x;
    int c = l >> 3, j = l & 7;
    float s = 0.f;
    for (int k = j * 16; k < j * 16 + 16; ++k) { float a = AV[c * 128 + k]; s += a * a; }
    s += __shfl_xor(s, 1); s += __shfl_xor(s, 2); s += __shfl_xor(s, 4);
    if (j == 0) v2[c] = s;
}

// ---------------- main fused kernel ----------------
// Block: 32 rows, 256 threads (4 waves), LDS 32KB. __launch_bounds__(256,4):
// 4 blocks/CU (16 waves, 50%), VGPR budget ~128 for deep load pipelining.
// Swapped GEMMs with mfma_f32_32x32x16_bf16:
//   GEMM1': h^T  = W1tp(A) @ x^T(B)   M=256 N=32 K=256   (wave wv: m-tiles 2wv,2wv+1)
//   GEMM2': act^T= W2tp(A) @ h(B)     M=128 N=32 K=256   (wave wv: m-tile wv)
//   GEMM3': D3   = B3p(A)  @ act(B)   M=32 N=32 K=128    (wave 0 only)
// LDS: x bf16 [32 rows][512B] @0; h @16384; act [32][256B] reuses @0; a2 partials @8192.
// Swizzle (FULL row width — row stride 512B aliases all rows to the same banks,
// so the XOR must cover all 32 rows, not row&7):
//   x/h tiles (32 chunks/row): 16B chunk c of row r at slot c^(r&31)
//   act tile  (16 chunks/row): slot c^(r&15)   (2 rows/bank-set -> 2-way = free)
#define LDS_H 16384

__global__ __launch_bounds__(256, 4)
void openmax_mfma(const float* __restrict__ x,
                  const float* __restrict__ b1, const float* __restrict__ b2,
                  const float* __restrict__ b3,
                  const float* __restrict__ walpha, const float* __restrict__ wbeta,
                  const float* __restrict__ wtau,
                  const short* __restrict__ wpack, const float* __restrict__ v2g,
                  float* __restrict__ out) {
    __shared__ __align__(16) char smem[32768];
    const int tid = threadIdx.x;
    const int l = tid & 63, wv = tid >> 6;
    const int lo = l & 31, g = l >> 5;
    const long row0 = (long)blockIdx.x * 32;

    // ---- stage x tile (32 rows x 256 f32) as bf16, swizzled ----
    {
        const float4* xg = (const float4*)(x + row0 * 256);
        #pragma unroll
        for (int i = 0; i < 8; ++i) {
            int fc = i * 256 + tid;          // f32 16B-chunk index (2048 total)
            float4 v = xg[fc];
            int row = fc >> 6, c4 = fc & 63;
            int cb = c4 >> 1, half = c4 & 1;
            short4v s;
            s[0] = f2bs(v.x); s[1] = f2bs(v.y); s[2] = f2bs(v.z); s[3] = f2bs(v.w);
            int off = row * 512 + ((cb ^ (row & 31)) << 4) + half * 8;
            *(short4v*)(smem + off) = s;
        }
    }
    __syncthreads();

    // ---- GEMM1': h^T = W1^T @ x^T ----
    {
        const int4v* Ap = (const int4v*)wpack;
        f32x16 acc0, acc1;
        #pragma unroll
        for (int i = 0; i < 16; ++i) { acc0[i] = 0.f; acc1[i] = 0.f; }
        const int mt0 = wv * 2;
        const int aRow = mt0 * 32 + lo;
        #pragma unroll
        for (int ks = 0; ks < 16; ++ks) {
            int kc = ks * 2 + g;
            short8 a0 = __builtin_bit_cast(short8, Ap[kc * 256 + aRow]);
            short8 a1 = __builtin_bit_cast(short8, Ap[kc * 256 + aRow + 32]);
            short8 bb = *(const short8*)(smem + lo * 512 + ((kc ^ (lo & 31)) << 4));
            acc0 = MFMA32(a0, bb, acc0);
            acc1 = MFMA32(a1, bb, acc1);
        }
        // bias + relu + pack to h LDS (b64 stores, swizzled -> conflict-free)
        #pragma unroll
        for (int mt = 0; mt < 2; ++mt) {
            const f32x16& A = (mt == 0) ? acc0 : acc1;
            float bia[16];
            #pragma unroll
            for (int r = 0; r < 16; ++r)
                bia[r] = b1[(mt0 + mt) * 32 + 4 * g + (r & 3) + 8 * (r >> 2)];
            int base = LDS_H + lo * 512 + g * 8;
            #pragma unroll
            for (int q = 0; q < 4; ++q) {
                float v0 = fmaxf(A[4 * q + 0] + bia[4 * q + 0], 0.f);
                float v1 = fmaxf(A[4 * q + 1] + bia[4 * q + 1], 0.f);
                float v2_ = fmaxf(A[4 * q + 2] + bia[4 * q + 2], 0.f);
                float v3 = fmaxf(A[4 * q + 3] + bia[4 * q + 3], 0.f);
                short4v s; s[0] = f2bs(v0); s[1] = f2bs(v1); s[2] = f2bs(v2_); s[3] = f2bs(v3);
                int hc = (mt0 + mt) * 4 + q;
                *(short4v*)(smem + base + ((hc ^ (lo & 31)) << 4)) = s;
            }
        }
    }
    __syncthreads();

    // ---- GEMM2': act^T = W2^T @ h ; act bf16 into dead x region + a2 partials ----
    {
        const int4v* Ap = (const int4v*)(wpack + 65536);
        f32x16 acc;
        #pragma unroll
        for (int i = 0; i < 16; ++i) acc[i] = 0.f;
        const int aRow = wv * 32 + lo;
        #pragma unroll
        for (int ks = 0; ks < 16; ++ks) {
            int kc = ks * 2 + g;
            short8 a = __builtin_bit_cast(short8, Ap[kc * 128 + aRow]);
            short8 bb = *(const short8*)(smem + LDS_H + lo * 512 + ((kc ^ (lo & 31)) << 4));
            acc = MFMA32(a, bb, acc);
        }
        float bia[16];
        #pragma unroll
        for (int r = 0; r < 16; ++r)
            bia[r] = b2[wv * 32 + 4 * g + (r & 3) + 8 * (r >> 2)];
        int base = lo * 256 + g * 8;
        float ss = 0.f;
        #pragma unroll
        for (int q = 0; q < 4; ++q) {
            float v0 = fmaxf(acc[4 * q + 0] + bia[4 * q + 0], 0.f);
            float v1 = fmaxf(acc[4 * q + 1] + bia[4 * q + 1], 0.f);
            float v2_ = fmaxf(acc[4 * q + 2] + bia[4 * q + 2], 0.f);
            float v3 = fmaxf(acc[4 * q + 3] + bia[4 * q + 3], 0.f);
            ss += v0 * v0 + v1 * v1 + v2_ * v2_ + v3 * v3;
            short4v s; s[0] = f2bs(v0); s[1] = f2bs(v1); s[2] = f2bs(v2_); s[3] = f2bs(v3);
            int hc = wv * 4 + q;
            *(short4v*)(smem + base + ((hc ^ (lo & 15)) << 4)) = s;
        }
        ss += __shfl_xor(ss, 32);
        if (g == 0) *(float*)(smem + 8192 + (wv * 32 + lo) * 4) = ss;
    }
    __syncthreads();

    // ---- GEMM3' + OpenMax epilogue (wave 0 only) ----
    if (wv == 0) {
        const int4v* Ap = (const int4v*)(wpack + 98304);
        f32x16 acc;
        #pragma unroll
        for (int i = 0; i < 16; ++i) acc[i] = 0.f;
        #pragma unroll
        for (int ks = 0; ks < 8; ++ks) {
            int kc = ks * 2 + g;
            short8 a = __builtin_bit_cast(short8, Ap[kc * 32 + lo]);
            short8 bb = *(const short8*)(smem + lo * 256 + ((kc ^ (lo & 15)) << 4));
            acc = MFMA32(a, bb, acc);
        }
        // lane holds: logits classes 4g+j in acc[j], dots classes 4g+j in acc[4+j]
        float oth[8];
        #pragma unroll
        for (int j = 0; j < 8; ++j) oth[j] = __shfl_xor(acc[j], 32);

        float a2v = 0.f;
        #pragma unroll
        for (int wq = 0; wq < 4; ++wq)
            a2v += *(const float*)(smem + 8192 + (wq * 32 + lo) * 4);

        float m = 0.f, outv[8];
        #pragma unroll
        for (int c = 0; c < 8; ++c) {
            float lgv = ((c >> 2) == g) ? acc[c & 3]       : oth[c & 3];
            float dtv = ((c >> 2) == g) ? acc[4 + (c & 3)] : oth[4 + (c & 3)];
            float d2 = a2v - 2.f * dtv + v2g[c];
            float dist = sqrtf(fmaxf(d2, 0.f));
            float sb = fmaxf(wbeta[c], 1e-6f);
            float sx = fmaxf(dist - wtau[c], 0.f);
            float cdf = 1.f - expf(-powf(sx / sb, walpha[c]));
            m = fmaxf(m, cdf);
            outv[c] = lgv + b3[c];
        }
        float scale = (m > 0.5f) ? (1.f - m) : 1.f;
        if (g == 0) {
            float4 o0 = { outv[0] * scale, outv[1] * scale, outv[2] * scale, outv[3] * scale };
            float4 o1 = { outv[4] * scale, outv[5] * scale, outv[6] * scale, outv[7] * scale };
            float4* op = (float4*)(out + (row0 + lo) * 8);
            op[0] = o0; op[1] = o1;
        }
    }
}

extern "C" void kernel_launch(void* const* d_in, const int* in_sizes, int n_in,
                              void* d_out, int out_size, void* d_ws, size_t ws_size,
                              hipStream_t stream) {
    const float* x      = (const float*)d_in[0];
    const float* W1     = (const float*)d_in[1];
    const float* b1     = (const float*)d_in[2];
    const float* W2     = (const float*)d_in[3];
    const float* b2     = (const float*)d_in[4];
    const float* W3     = (const float*)d_in[5];
    const float* b3     = (const float*)d_in[6];
    const float* walpha = (const float*)d_in[7];
    const float* wbeta  = (const float*)d_in[8];
    const float* wtau   = (const float*)d_in[9];
    const float* AV     = (const float*)d_in[10];
    float* out = (float*)d_out;

    short* wpack = (short*)d_ws;
    float* v2    = (float*)((char*)d_ws + 204800);

    prep_pack<<<400, 256, 0, stream>>>(W1, W2, W3, AV, wpack);
    prep_v2<<<1, 64, 0, stream>>>(AV, v2);

    const int B = in_sizes[0] / 256;   // 262144
    openmax_mfma<<<B / 32, 256, 0, stream>>>(x, b1, b2, b3, walpha, wbeta, wtau,
                                             wpack, v2, out);
}

// Round 6
// 108.890 us; speedup vs baseline: 21.9510x; 1.1246x over previous
//
#include <hip/hip_runtime.h>
#include <hip/hip_bf16.h>
#include <math.h>

typedef __attribute__((ext_vector_type(8)))  short  short8;
typedef __attribute__((ext_vector_type(4)))  short  short4v;
typedef __attribute__((ext_vector_type(16))) float  f32x16;
typedef __attribute__((ext_vector_type(4)))  int    int4v;

__device__ __forceinline__ short f2bs(float f) {
    __hip_bfloat16 h = __float2bfloat16(f);
    return __builtin_bit_cast(short, h);
}

#define MFMA32(A, B, C) __builtin_amdgcn_mfma_f32_32x32x16_bf16((A), (B), (C), 0, 0, 0)

// ---------------- ws layout (bytes) ----------------
//   [0, 131072)       W1tp: [kc 0..31][m 0..255][8] bf16 = W1[(kc*8+i)*256+m]
//   [131072, 196608)  W2tp: [kc 0..31][m 0..127][8] bf16 = W2[(kc*8+i)*128+m]
//   [196608, 204800)  B3p : [kc 0..15][m 0..31 ][8] bf16, m<8: W3[k*8+m]; 8..15: AV[(m-8)*128+k]; else 0
//   [204800, 204832)  v2  : float[8] = sum_k AV[c][k]^2
//   [204832, 205856)  b1p : float[256], b1p[(mtile*2+g)*16+r] = b1[mtile*32+4g+(r&3)+8*(r>>2)]
//   [205856, 206368)  b2p : float[128], same mapping for b2 (mtile 0..3)

__global__ void prep_pack(const float* __restrict__ W1, const float* __restrict__ W2,
                          const float* __restrict__ W3, const float* __restrict__ AV,
                          short* __restrict__ wp) {
    int j = blockIdx.x * 256 + threadIdx.x;   // one short8 fragment per thread
    if (j < 8192) {                            // W1tp
        int kc = j >> 8, m = j & 255;
        short8 s;
        #pragma unroll
        for (int i = 0; i < 8; ++i) s[i] = f2bs(W1[(kc * 8 + i) * 256 + m]);
        *(short8*)(wp + (size_t)j * 8) = s;
    } else if (j < 12288) {                    // W2tp
        int jj = j - 8192; int kc = jj >> 7, m = jj & 127;
        short8 s;
        #pragma unroll
        for (int i = 0; i < 8; ++i) s[i] = f2bs(W2[(kc * 8 + i) * 128 + m]);
        *(short8*)(wp + 65536 + (size_t)jj * 8) = s;
    } else if (j < 12800) {                    // B3p
        int jj = j - 12288; int kc = jj >> 5, m = jj & 31;
        short8 s;
        #pragma unroll
        for (int i = 0; i < 8; ++i) {
            int k = kc * 8 + i;
            float v = 0.f;
            if (m < 8)       v = W3[k * 8 + m];
            else if (m < 16) v = AV[(m - 8) * 128 + k];
            s[i] = f2bs(v);
        }
        *(short8*)(wp + 98304 + (size_t)jj * 8) = s;
    }
}

__global__ void prep_small(const float* __restrict__ AV, const float* __restrict__ b1,
                           const float* __restrict__ b2, float* __restrict__ v2,
                           float* __restrict__ b1p, float* __restrict__ b2p) {
    int t = threadIdx.x;   // 256 threads
    {
        int mt = t >> 5, g = (t >> 4) & 1, r = t & 15;
        b1p[t] = b1[mt * 32 + 4 * g + (r & 3) + 8 * (r >> 2)];
    }
    if (t < 128) {
        int mt = t >> 5, g = (t >> 4) & 1, r = t & 15;
        b2p[t] = b2[mt * 32 + 4 * g + (r & 3) + 8 * (r >> 2)];
    }
    if (t < 64) {
        int c = t >> 3, jj = t & 7;
        float s = 0.f;
        for (int k = jj * 16; k < jj * 16 + 16; ++k) { float a = AV[c * 128 + k]; s = fmaf(a, a, s); }
        s += __shfl_xor(s, 1); s += __shfl_xor(s, 2); s += __shfl_xor(s, 4);
        if (jj == 0) v2[c] = s;
    }
}

// ---------------- main fused kernel ----------------
// Block: 32 rows, 4 waves, 32KB LDS. Swapped GEMMs, mfma_f32_32x32x16_bf16.
// Explicit 4-deep software pipeline on A (global, vmcnt) and B (LDS, lgkmcnt)
// fragments; cross-phase prefetch issues next phase's A before each barrier.
// Swizzle: 16B chunk c of row r at slot c^r (x/h, 32 chunks) or c^(r&15) (act).
#define LDS_H 16384

__global__ __launch_bounds__(256, 4)
void openmax_mfma(const float* __restrict__ x,
                  const float* __restrict__ b3,
                  const float* __restrict__ walpha, const float* __restrict__ wbeta,
                  const float* __restrict__ wtau,
                  const short* __restrict__ wpack, const float* __restrict__ v2g,
                  const float* __restrict__ b1p, const float* __restrict__ b2p,
                  float* __restrict__ out) {
    __shared__ __align__(16) char smem[32768];
    const int tid = threadIdx.x;
    const int l = tid & 63, wv = tid >> 6;
    const int lo = l & 31, g = l >> 5;
    const long row0 = (long)blockIdx.x * 32;

    const int4v* Ap1 = (const int4v*)wpack;
    const int4v* Ap2 = (const int4v*)(wpack + 65536);
    const int4v* Ap3 = (const int4v*)(wpack + 98304);

    // ---- issue x loads first (HBM critical path) ----
    const float4* xg = (const float4*)(x + row0 * 256);
    float4 xv[8];
    #pragma unroll
    for (int i = 0; i < 8; ++i) xv[i] = xg[i * 256 + tid];

    // ---- GEMM1 A prefetch (L2) while x is in flight ----
    const int aRow1 = wv * 64 + lo;
    short8 pa0[4], pa1[4];
    #pragma unroll
    for (int p = 0; p < 4; ++p) {
        int kc = p * 2 + g;
        pa0[p] = __builtin_bit_cast(short8, Ap1[kc * 256 + aRow1]);
        pa1[p] = __builtin_bit_cast(short8, Ap1[kc * 256 + aRow1 + 32]);
    }

    // ---- convert + store x tile (waits x loads; A stays in flight) ----
    {
        #pragma unroll
        for (int i = 0; i < 8; ++i) {
            int fc = i * 256 + tid;
            int row = fc >> 6, c4 = fc & 63;
            int cb = c4 >> 1, half = c4 & 1;
            short4v s;
            s[0] = f2bs(xv[i].x); s[1] = f2bs(xv[i].y); s[2] = f2bs(xv[i].z); s[3] = f2bs(xv[i].w);
            int off = row * 512 + ((cb ^ row) << 4) + half * 8;
            *(short4v*)(smem + off) = s;
        }
    }
    __syncthreads();

    // ---- GEMM1': h^T = W1^T @ x^T  (16 ks, 4-deep pipeline) ----
    {
        short8 pb[4];
        #pragma unroll
        for (int p = 0; p < 4; ++p) {
            int kc = p * 2 + g;
            pb[p] = *(const short8*)(smem + lo * 512 + ((kc ^ lo) << 4));
        }
        f32x16 acc0, acc1;
        #pragma unroll
        for (int i = 0; i < 16; ++i) { acc0[i] = 0.f; acc1[i] = 0.f; }
        #pragma unroll
        for (int ks = 0; ks < 16; ++ks) {
            const int slot = ks & 3;
            short8 a0 = pa0[slot], a1 = pa1[slot], bb = pb[slot];
            if (ks < 12) {
                int kc = (ks + 4) * 2 + g;
                pa0[slot] = __builtin_bit_cast(short8, Ap1[kc * 256 + aRow1]);
                pa1[slot] = __builtin_bit_cast(short8, Ap1[kc * 256 + aRow1 + 32]);
                pb[slot]  = *(const short8*)(smem + lo * 512 + ((kc ^ lo) << 4));
            }
            acc0 = MFMA32(a0, bb, acc0);
            acc1 = MFMA32(a1, bb, acc1);
        }
        // bias (packed, float4) + relu + store h
        #pragma unroll
        for (int mt = 0; mt < 2; ++mt) {
            const f32x16& A = (mt == 0) ? acc0 : acc1;
            const float* bp = b1p + ((wv * 2 + mt) * 2 + g) * 16;
            float4 B0 = *(const float4*)(bp);
            float4 B1 = *(const float4*)(bp + 4);
            float4 B2 = *(const float4*)(bp + 8);
            float4 B3_ = *(const float4*)(bp + 12);
            float bia[16];
            *(float4*)(bia)      = B0; *(float4*)(bia + 4)  = B1;
            *(float4*)(bia + 8)  = B2; *(float4*)(bia + 12) = B3_;
            int base = LDS_H + lo * 512 + g * 8;
            #pragma unroll
            for (int q = 0; q < 4; ++q) {
                float v0 = fmaxf(A[4 * q + 0] + bia[4 * q + 0], 0.f);
                float v1 = fmaxf(A[4 * q + 1] + bia[4 * q + 1], 0.f);
                float v2_ = fmaxf(A[4 * q + 2] + bia[4 * q + 2], 0.f);
                float v3 = fmaxf(A[4 * q + 3] + bia[4 * q + 3], 0.f);
                short4v s; s[0] = f2bs(v0); s[1] = f2bs(v1); s[2] = f2bs(v2_); s[3] = f2bs(v3);
                int hc = (wv * 2 + mt) * 4 + q;
                *(short4v*)(smem + base + ((hc ^ lo) << 4)) = s;
            }
        }
    }

    // ---- GEMM2 A prefetch BEFORE barrier (no LDS dependency) ----
    const int aRow2 = wv * 32 + lo;
    short8 pa2[4];
    #pragma unroll
    for (int p = 0; p < 4; ++p) {
        int kc = p * 2 + g;
        pa2[p] = __builtin_bit_cast(short8, Ap2[kc * 128 + aRow2]);
    }
    __syncthreads();

    // ---- GEMM2': act^T = W2^T @ h  (16 ks, 4-deep pipeline) ----
    {
        short8 pb[4];
        #pragma unroll
        for (int p = 0; p < 4; ++p) {
            int kc = p * 2 + g;
            pb[p] = *(const short8*)(smem + LDS_H + lo * 512 + ((kc ^ lo) << 4));
        }
        f32x16 acc;
        #pragma unroll
        for (int i = 0; i < 16; ++i) acc[i] = 0.f;
        #pragma unroll
        for (int ks = 0; ks < 16; ++ks) {
            const int slot = ks & 3;
            short8 a = pa2[slot], bb = pb[slot];
            if (ks < 12) {
                int kc = (ks + 4) * 2 + g;
                pa2[slot] = __builtin_bit_cast(short8, Ap2[kc * 128 + aRow2]);
                pb[slot]  = *(const short8*)(smem + LDS_H + lo * 512 + ((kc ^ lo) << 4));
            }
            acc = MFMA32(a, bb, acc);
        }
        const float* bp = b2p + (wv * 2 + g) * 16;
        float4 B0 = *(const float4*)(bp);
        float4 B1 = *(const float4*)(bp + 4);
        float4 B2 = *(const float4*)(bp + 8);
        float4 B3_ = *(const float4*)(bp + 12);
        float bia[16];
        *(float4*)(bia)      = B0; *(float4*)(bia + 4)  = B1;
        *(float4*)(bia + 8)  = B2; *(float4*)(bia + 12) = B3_;
        int base = lo * 256 + g * 8;
        float ss = 0.f;
        #pragma unroll
        for (int q = 0; q < 4; ++q) {
            float v0 = fmaxf(acc[4 * q + 0] + bia[4 * q + 0], 0.f);
            float v1 = fmaxf(acc[4 * q + 1] + bia[4 * q + 1], 0.f);
            float v2_ = fmaxf(acc[4 * q + 2] + bia[4 * q + 2], 0.f);
            float v3 = fmaxf(acc[4 * q + 3] + bia[4 * q + 3], 0.f);
            ss += v0 * v0 + v1 * v1 + v2_ * v2_ + v3 * v3;
            short4v s; s[0] = f2bs(v0); s[1] = f2bs(v1); s[2] = f2bs(v2_); s[3] = f2bs(v3);
            int hc = wv * 4 + q;
            *(short4v*)(smem + base + ((hc ^ (lo & 15)) << 4)) = s;
        }
        ss += __shfl_xor(ss, 32);
        if (g == 0) *(float*)(smem + 8192 + (wv * 32 + lo) * 4) = ss;
    }

    // ---- GEMM3 A preload + epilogue constants BEFORE barrier (wave 0) ----
    short8 pa3[8];
    float4 e_b3[2], e_v2[2], e_al[2], e_be[2], e_ta[2];
    if (wv == 0) {
        #pragma unroll
        for (int p = 0; p < 8; ++p) {
            int kc = p * 2 + g;
            pa3[p] = __builtin_bit_cast(short8, Ap3[kc * 32 + lo]);
        }
        e_b3[0] = *(const float4*)(b3);     e_b3[1] = *(const float4*)(b3 + 4);
        e_v2[0] = *(const float4*)(v2g);    e_v2[1] = *(const float4*)(v2g + 4);
        e_al[0] = *(const float4*)(walpha); e_al[1] = *(const float4*)(walpha + 4);
        e_be[0] = *(const float4*)(wbeta);  e_be[1] = *(const float4*)(wbeta + 4);
        e_ta[0] = *(const float4*)(wtau);   e_ta[1] = *(const float4*)(wtau + 4);
    }
    __syncthreads();

    // ---- GEMM3' + OpenMax epilogue (wave 0 only) ----
    if (wv == 0) {
        short8 pb[8];
        #pragma unroll
        for (int p = 0; p < 8; ++p) {
            int kc = p * 2 + g;
            pb[p] = *(const short8*)(smem + lo * 256 + ((kc ^ (lo & 15)) << 4));
        }
        f32x16 acc;
        #pragma unroll
        for (int i = 0; i < 16; ++i) acc[i] = 0.f;
        #pragma unroll
        for (int ks = 0; ks < 8; ++ks)
            acc = MFMA32(pa3[ks], pb[ks], acc);

        float oth[8];
        #pragma unroll
        for (int j = 0; j < 8; ++j) oth[j] = __shfl_xor(acc[j], 32);

        float a2v = 0.f;
        #pragma unroll
        for (int wq = 0; wq < 4; ++wq)
            a2v += *(const float*)(smem + 8192 + (wq * 32 + lo) * 4);

        float m = 0.f, outv[8];
        #pragma unroll
        for (int c = 0; c < 8; ++c) {
            float lgv = ((c >> 2) == g) ? acc[c & 3]       : oth[c & 3];
            float dtv = ((c >> 2) == g) ? acc[4 + (c & 3)] : oth[4 + (c & 3)];
            float v2c = e_v2[c >> 2][c & 3];
            float d2 = a2v - 2.f * dtv + v2c;
            float dist = sqrtf(fmaxf(d2, 0.f));
            float sb = fmaxf(e_be[c >> 2][c & 3], 1e-6f);
            float sx = fmaxf(dist - e_ta[c >> 2][c & 3], 0.f);
            float t = sx / sb;
            float y = exp2f(e_al[c >> 2][c & 3] * log2f(t));   // t^alpha (t=0 -> -inf -> 0)
            float cdf = 1.f - expf(-y);
            m = fmaxf(m, cdf);
            outv[c] = lgv + e_b3[c >> 2][c & 3];
        }
        float scale = (m > 0.5f) ? (1.f - m) : 1.f;
        if (g == 0) {
            float4 o0 = { outv[0] * scale, outv[1] * scale, outv[2] * scale, outv[3] * scale };
            float4 o1 = { outv[4] * scale, outv[5] * scale, outv[6] * scale, outv[7] * scale };
            float4* op = (float4*)(out + (row0 + lo) * 8);
            op[0] = o0; op[1] = o1;
        }
    }
}

extern "C" void kernel_launch(void* const* d_in, const int* in_sizes, int n_in,
                              void* d_out, int out_size, void* d_ws, size_t ws_size,
                              hipStream_t stream) {
    const float* x      = (const float*)d_in[0];
    const float* W1     = (const float*)d_in[1];
    const float* b1     = (const float*)d_in[2];
    const float* W2     = (const float*)d_in[3];
    const float* b2     = (const float*)d_in[4];
    const float* W3     = (const float*)d_in[5];
    const float* b3     = (const float*)d_in[6];
    const float* walpha = (const float*)d_in[7];
    const float* wbeta  = (const float*)d_in[8];
    const float* wtau   = (const float*)d_in[9];
    const float* AV     = (const float*)d_in[10];
    float* out = (float*)d_out;

    short* wpack = (short*)d_ws;
    float* v2    = (float*)((char*)d_ws + 204800);
    float* b1p   = (float*)((char*)d_ws + 204832);
    float* b2p   = (float*)((char*)d_ws + 205856);

    prep_pack<<<50, 256, 0, stream>>>(W1, W2, W3, AV, wpack);
    prep_small<<<1, 256, 0, stream>>>(AV, b1, b2, v2, b1p, b2p);

    const int B = in_sizes[0] / 256;   // 262144
    openmax_mfma<<<B / 32, 256, 0, stream>>>(x, b3, walpha, wbeta, wtau,
                                             wpack, v2, b1p, b2p, out);
}